// Round 5
// baseline (118.078 us; speedup 1.0000x reference)
//
#include <hip/hip_runtime.h>

// Fully fused 3-level db4 wavedec (periodization) over (B=64, N=4096, F=64) f32.
// v5: write-stream consolidation. v2/v4 showed the kernel is NOT bound by
// load latency (48-deep prefetch: null), VMEM width (float2: null), or VALU
// (~5 us total). Remaining theory: the per-wave store stream interleaves 4
// output regions (d1,d1,d2,a3/d3 cycling every 4 steps) at 256 B granularity
// -> ~16k concurrently-advancing tiny write streams chip-wide vs the fill
// kernel's one-huge-stream pattern at 6.5 TB/s. v5 accumulates ALL outputs in
// registers during the cascade and writes them in a bulk epilogue: 4 clean
// sequential bursts per thread (d1: 32 rows, d2: 16, a3: 8, d3: 8).
// Traffic identical (134 MB compulsory), schedule identical, only store
// ordering changes.
//
// (Round 4: resubmission — Round 3's bench died on container acquire, the
// experiment never ran.)
//
// c[k] = sum_j filt[j] * x[(2k+1-j) mod N]  ==  sum_m w[m]*filtR[m],
// where w[m] = x[(2k-6+m) mod N] and filtR[m] = filt[7-m].
//
// Output rows: [0,512)=cA3, [512,1024)=cD3, [1024,2048)=cD2, [2048,4096)=cD1.
// Own ranges never wrap: i1 in [4K3, 4K3+32) < 2048, i2 in [2K3, 2K3+16) < 1024,
// i3 in [K3, K3+8) < 512.

__device__ __forceinline__ float2 ld2(const float* p) {
    return *reinterpret_cast<const float2*>(p);
}
__device__ __forceinline__ void st2(float* p, float2 v) {
    *reinterpret_cast<float2*>(p) = v;
}
__device__ __forceinline__ float2 fma2(float2 a, float s, float2 c) {
    c.x = fmaf(a.x, s, c.x);
    c.y = fmaf(a.y, s, c.y);
    return c;
}

__global__ __launch_bounds__(256, 2) void dwt3_fused_v5(
    const float* __restrict__ in,   // (64, 4096, 64)
    float* __restrict__ out)        // (64, 4096, 64)
{
    // reversed filters (filtR[m] = filt[7-m])
    const float LOR[8] = { 0.23037781330885523f,   0.7148465705525415f,
                           0.6308807679295904f,   -0.02798376941698385f,
                          -0.18703481171888114f,   0.030841381835986965f,
                           0.032883011666982945f, -0.010597401784997278f};
    const float HIR[8] = {-0.010597401784997278f, -0.032883011666982945f,
                           0.030841381835986965f,  0.18703481171888114f,
                          -0.02798376941698385f,  -0.6308807679295904f,
                           0.7148465705525415f,   -0.23037781330885523f};

    // XCD-aware swizzle: 512 blocks, 8 XCDs, 64 contiguous blocks per XCD.
    const int bid  = blockIdx.x;
    const int swz  = (bid & 7) * 64 + (bid >> 3);

    const int lane = threadIdx.x & 63;
    const int wv   = threadIdx.x >> 6;              // wave within block (0..3)
    const int f    = (lane & 31) * 2;               // f-pair base column
    const int tsub = lane >> 5;                     // which tile half of the wave
    const int b    = swz >> 3;                      // 64 batches
    const int tile = (swz & 7) * 8 + wv * 2 + tsub; // 64 tiles of T3=8 per batch
    const int K3   = tile * 8;

    const float* inB  = in  + (size_t)b * 4096 * 64 + f;
    float*       outB = out + (size_t)b * 4096 * 64 + f;

    const int i1s = 4 * K3 - 18;   // first level-1 index produced (even)

    float2 w0[8];                  // rolling window x[(2*i1-6 .. 2*i1+1) mod N]
    float2 w1[8];                  // last 8 cA1 values
    float2 w2[8];                  // last 8 cA2 values
    #pragma unroll
    for (int m = 0; m < 8; ++m) {
        w1[m] = make_float2(0.f, 0.f);
        w2[m] = make_float2(0.f, 0.f);
    }

    // Output accumulators (bulk-written in epilogue).
    float2 d1acc[32], d2acc[16], a3acc[8], d3acc[8];

    #pragma unroll
    for (int m = 0; m < 8; ++m) {
        const int r = (2 * i1s - 6 + m) & 4095;
        w0[m] = ld2(inB + (size_t)r * 64);
    }

    #pragma unroll
    for (int s = 0; s < 50; ++s) {
        const int i1 = i1s + s;
        if (s > 0) {
            #pragma unroll
            for (int m = 0; m < 6; ++m) w0[m] = w0[m + 2];
            const int ra = (2 * i1)     & 4095;
            const int rb = (2 * i1 + 1) & 4095;
            w0[6] = ld2(inB + (size_t)ra * 64);
            w0[7] = ld2(inB + (size_t)rb * 64);
        }

        // ---- level 1 ----
        float2 a1 = make_float2(0.f, 0.f);
        #pragma unroll
        for (int m = 0; m < 8; ++m) a1 = fma2(w0[m], LOR[m], a1);
        if (s >= 18) {                       // i1 in own range [4K3, 4K3+32)
            float2 d1 = make_float2(0.f, 0.f);
            #pragma unroll
            for (int m = 0; m < 8; ++m) d1 = fma2(w0[m], HIR[m], d1);
            d1acc[s - 18] = d1;
        }
        #pragma unroll
        for (int m = 0; m < 7; ++m) w1[m] = w1[m + 1];
        w1[7] = a1;

        // ---- level 2: emit when i1 = 2*i2+1 (s odd) and window full ----
        if ((s & 1) && s >= 7) {
            float2 a2 = make_float2(0.f, 0.f);
            #pragma unroll
            for (int m = 0; m < 8; ++m) a2 = fma2(w1[m], LOR[m], a2);
            if (s >= 19) {                   // i2 in own range [2K3, 2K3+16)
                float2 d2 = make_float2(0.f, 0.f);
                #pragma unroll
                for (int m = 0; m < 8; ++m) d2 = fma2(w1[m], HIR[m], d2);
                d2acc[(s - 19) / 2] = d2;
            }
            #pragma unroll
            for (int m = 0; m < 7; ++m) w2[m] = w2[m + 1];
            w2[7] = a2;

            // ---- level 3: emit when i2 = 2*i3+1 and window full ----
            if (s >= 21 && ((s - 21) & 3) == 0) {
                float2 a3 = make_float2(0.f, 0.f);
                float2 d3 = make_float2(0.f, 0.f);
                #pragma unroll
                for (int m = 0; m < 8; ++m) {
                    a3 = fma2(w2[m], LOR[m], a3);
                    d3 = fma2(w2[m], HIR[m], d3);
                }
                a3acc[(s - 21) / 4] = a3;
                d3acc[(s - 21) / 4] = d3;
            }
        }
    }

    // ---- bulk epilogue: 4 clean sequential write bursts per thread ----
    {
        float* p = outB + (size_t)(2048 + 4 * K3) * 64;   // cD1, 32 rows
        #pragma unroll
        for (int t = 0; t < 32; ++t) st2(p + (size_t)t * 64, d1acc[t]);
    }
    {
        float* p = outB + (size_t)(1024 + 2 * K3) * 64;   // cD2, 16 rows
        #pragma unroll
        for (int u = 0; u < 16; ++u) st2(p + (size_t)u * 64, d2acc[u]);
    }
    {
        float* p = outB + (size_t)K3 * 64;                // cA3, 8 rows
        #pragma unroll
        for (int v = 0; v < 8; ++v) st2(p + (size_t)v * 64, a3acc[v]);
    }
    {
        float* p = outB + (size_t)(512 + K3) * 64;        // cD3, 8 rows
        #pragma unroll
        for (int v = 0; v < 8; ++v) st2(p + (size_t)v * 64, d3acc[v]);
    }
}

extern "C" void kernel_launch(void* const* d_in, const int* in_sizes, int n_in,
                              void* d_out, int out_size, void* d_ws, size_t ws_size,
                              hipStream_t stream) {
    (void)in_sizes; (void)n_in; (void)out_size; (void)d_ws; (void)ws_size;
    const float* x = (const float*)d_in[0];
    float* out = (float*)d_out;
    // 64 batches * 8 block-groups (4 waves/block * 2 tiles/wave, T3=8) = 512 blocks
    dwt3_fused_v5<<<512, 256, 0, stream>>>(x, out);
}

// Round 6
// 113.723 us; speedup vs baseline: 1.0383x; 1.0383x over previous
//
#include <hip/hip_runtime.h>

// Fully fused 3-level db4 wavedec (periodization) over (B=64, N=4096, F=64) f32.
// v6: halo-traffic reduction. v2-v5 falsified width/TLP/MLP/store-order
// theories (all ~33-34 us). Surviving model: kernel runs at a fixed ~5.3 TB/s
// of INSTRUCTION-LEVEL traffic; T3=8's cascade warmup re-reads 106 rows per
// 64 produced (1.66x read amp, 178 MB total). v6: T3=16 -> 170 rows per 128
// produced (1.33x, 156 MB total, 0.88x). Occupancy kept at 2 waves/SIMD by
// using ONE tile per full wave (scalar f32 per lane, 64 lanes = 64 f-columns;
// v2 showed scalar vs float2 is perf-neutral). Same grid: 512 blocks x 256.
//
// c[k] = sum_j filt[j] * x[(2k+1-j) mod N]  ==  sum_m w[m]*filtR[m],
// where w[m] = x[(2k-6+m) mod N] and filtR[m] = filt[7-m].
//
// Output rows: [0,512)=cA3, [512,1024)=cD3, [1024,2048)=cD2, [2048,4096)=cD1.
// Own output ranges never wrap (i1<2048, i2<1024, i3<512) -> no mask on stores.
// Input rows span [8K3-42, 8K3+128) -> masked & 4095 (wraps at both ends).

__global__ __launch_bounds__(256, 2) void dwt3_fused_v6(
    const float* __restrict__ in,   // (64, 4096, 64)
    float* __restrict__ out)        // (64, 4096, 64)
{
    // reversed filters (filtR[m] = filt[7-m])
    const float LOR[8] = { 0.23037781330885523f,   0.7148465705525415f,
                           0.6308807679295904f,   -0.02798376941698385f,
                          -0.18703481171888114f,   0.030841381835986965f,
                           0.032883011666982945f, -0.010597401784997278f};
    const float HIR[8] = {-0.010597401784997278f, -0.032883011666982945f,
                           0.030841381835986965f,  0.18703481171888114f,
                          -0.02798376941698385f,  -0.6308807679295904f,
                           0.7148465705525415f,   -0.23037781330885523f};

    // XCD-aware swizzle: 512 blocks, 8 XCDs, 64 contiguous blocks per XCD.
    const int bid  = blockIdx.x;
    const int swz  = (bid & 7) * 64 + (bid >> 3);

    const int f    = threadIdx.x & 63;             // one f-column per lane
    const int wv   = threadIdx.x >> 6;             // wave within block (0..3)
    const int b    = swz >> 3;                     // 64 batches
    const int tile = (swz & 7) * 4 + wv;           // 32 tiles of T3=16 per batch
    const int K3   = tile * 16;

    const float* inB  = in  + (size_t)b * 4096 * 64 + f;
    float*       outB = out + (size_t)b * 4096 * 64 + f;

    const int i1s = 4 * K3 - 18;   // first level-1 index produced (even)

    float w0[8];                       // rolling window x[(2*i1-6 .. 2*i1+1) mod N]
    float w1[8] = {0,0,0,0,0,0,0,0};   // last 8 cA1 values
    float w2[8] = {0,0,0,0,0,0,0,0};   // last 8 cA2 values

    #pragma unroll
    for (int m = 0; m < 8; ++m) {
        const int r = (2 * i1s - 6 + m) & 4095;
        w0[m] = inB[(size_t)r * 64];
    }

    #pragma unroll
    for (int s = 0; s < 82; ++s) {
        const int i1 = i1s + s;
        if (s > 0) {
            #pragma unroll
            for (int m = 0; m < 6; ++m) w0[m] = w0[m + 2];
            const int ra = (2 * i1)     & 4095;
            const int rb = (2 * i1 + 1) & 4095;
            w0[6] = inB[(size_t)ra * 64];
            w0[7] = inB[(size_t)rb * 64];
        }

        // ---- level 1 ----
        float a1 = 0.f;
        #pragma unroll
        for (int m = 0; m < 8; ++m) a1 = fmaf(w0[m], LOR[m], a1);
        if (s >= 18) {                       // i1 in own range [4K3, 4K3+64)
            float d1 = 0.f;
            #pragma unroll
            for (int m = 0; m < 8; ++m) d1 = fmaf(w0[m], HIR[m], d1);
            outB[(size_t)(2048 + i1) * 64] = d1;
        }
        #pragma unroll
        for (int m = 0; m < 7; ++m) w1[m] = w1[m + 1];
        w1[7] = a1;

        // ---- level 2: emit when i1 = 2*i2+1 (s odd) and window full ----
        if ((s & 1) && s >= 7) {
            const int i2 = 2 * K3 + (s - 19) / 2;   // exact for odd s
            float a2 = 0.f;
            #pragma unroll
            for (int m = 0; m < 8; ++m) a2 = fmaf(w1[m], LOR[m], a2);
            if (s >= 19) {                   // i2 in own range [2K3, 2K3+32)
                float d2 = 0.f;
                #pragma unroll
                for (int m = 0; m < 8; ++m) d2 = fmaf(w1[m], HIR[m], d2);
                outB[(size_t)(1024 + i2) * 64] = d2;
            }
            #pragma unroll
            for (int m = 0; m < 7; ++m) w2[m] = w2[m + 1];
            w2[7] = a2;

            // ---- level 3: emit when i2 = 2*i3+1 and window full ----
            if (s >= 21 && ((s - 21) & 3) == 0) {
                const int i3 = K3 + (s - 21) / 4;    // own range [K3, K3+16)
                float a3 = 0.f, d3 = 0.f;
                #pragma unroll
                for (int m = 0; m < 8; ++m) {
                    a3 = fmaf(w2[m], LOR[m], a3);
                    d3 = fmaf(w2[m], HIR[m], d3);
                }
                outB[(size_t)i3 * 64]         = a3;
                outB[(size_t)(512 + i3) * 64] = d3;
            }
        }
    }
}

extern "C" void kernel_launch(void* const* d_in, const int* in_sizes, int n_in,
                              void* d_out, int out_size, void* d_ws, size_t ws_size,
                              hipStream_t stream) {
    (void)in_sizes; (void)n_in; (void)out_size; (void)d_ws; (void)ws_size;
    const float* x = (const float*)d_in[0];
    float* out = (float*)d_out;
    // 64 batches * 8 block-groups (4 waves/block, 1 tile/wave, T3=16) = 512 blocks
    dwt3_fused_v6<<<512, 256, 0, stream>>>(x, out);
}